// Round 3
// baseline (1106.268 us; speedup 1.0000x reference)
//
#include <hip/hip_runtime.h>
#include <math.h>

#define U_N 10000
#define G_N 3000
#define I_N 8000
#define D_N 32
#define NNZ_UI 720000
#define NNZ_GI 440000
#define L_MEM 20
#define B_N 4096
#define UI_N (U_N + I_N)   // 18000
#define GI_N (G_N + I_N)   // 11000
#define CAP 128            // max degree (Poisson(40); P(>128) ~ 1e-26)

static __host__ int cdiv(int a, int b) { return (a + b - 1) / b; }

typedef __attribute__((ext_vector_type(8))) short bf16x8;
typedef __attribute__((ext_vector_type(4))) float f32x4;

__device__ __forceinline__ short f32_to_bf16(float f) {
    unsigned u = __float_as_uint(f);
    unsigned r = (u + 0x7FFFu + ((u >> 16) & 1u)) >> 16;   // RTNE
    return (short)r;
}

// ---------------- sparse: bucket build (both graphs), one launch ----------------

__global__ __launch_bounds__(256) void bucket_fill2(const int* __restrict__ uir,
                                                    const int* __restrict__ uic,
                                                    const float* __restrict__ uiv,
                                                    const int* __restrict__ gir,
                                                    const int* __restrict__ gic,
                                                    const float* __restrict__ giv,
                                                    int* __restrict__ cnt_ui,
                                                    int* __restrict__ cnt_gi,
                                                    int2* __restrict__ bkt_ui,
                                                    int2* __restrict__ bkt_gi) {
    int i = blockIdx.x * 256 + threadIdx.x;
    if (i < NNZ_UI) {
        int r = uir[i];
        int pos = atomicAdd(&cnt_ui[r], 1);
        if (pos < CAP) {
            int2 e; e.x = uic[i]; e.y = __float_as_int(uiv[i]);
            bkt_ui[(size_t)r * CAP + pos] = e;
        }
        return;
    }
    int k = i - NNZ_UI;
    if (k < NNZ_GI) {
        int r = gir[k];
        int pos = atomicAdd(&cnt_gi[r], 1);
        if (pos < CAP) {
            int2 e; e.x = gic[k]; e.y = __float_as_int(giv[k]);
            bkt_gi[(size_t)r * CAP + pos] = e;
        }
    }
}

// ---------------- split-source gather SPMM ----------------
#define GATHER(e) ((e.x < split) ? x1[(size_t)e.x * 32 + d] \
                                 : x2[(size_t)(e.x - split) * 32 + d])

// out[row,d] = sum_j val_j * X[col_j, d], X = concat(x1[0:split], x2[...]).
__global__ __launch_bounds__(256) void spmm_split(const int* __restrict__ cnt,
                                                  const int2* __restrict__ bkt,
                                                  const float* __restrict__ x1,
                                                  const float* __restrict__ x2,
                                                  int split,
                                                  float* __restrict__ out, int nrows) {
    int row = blockIdx.x * 8 + (threadIdx.x >> 5);
    if (row >= nrows) return;
    int d = threadIdx.x & 31;
    int deg = cnt[row];
    if (deg > CAP) deg = CAP;
    const int2* bk = bkt + (size_t)row * CAP;
    float acc = 0.f;
    int j = 0;
    for (; j + 3 < deg; j += 4) {
        int2 e0 = bk[j], e1 = bk[j + 1], e2 = bk[j + 2], e3 = bk[j + 3];
        float g0 = GATHER(e0), g1 = GATHER(e1), g2 = GATHER(e2), g3 = GATHER(e3);
        acc = fmaf(__int_as_float(e0.y), g0, acc);
        acc = fmaf(__int_as_float(e1.y), g1, acc);
        acc = fmaf(__int_as_float(e2.y), g2, acc);
        acc = fmaf(__int_as_float(e3.y), g3, acc);
    }
    for (; j < deg; ++j) {
        int2 e = bk[j];
        acc = fmaf(__int_as_float(e.y), GATHER(e), acc);
    }
    out[(size_t)row * 32 + d] = acc;
}

// gt1 (rows 0..G-1, x2=iemb0) and gt3 (rows G..2G-1 of virtual space, x2=ui2 item part)
// merged into one launch; both use bkt_gi rows < G, x1=gemb0, split=G_N.
__global__ __launch_bounds__(256) void spmm_g2(const int* __restrict__ cnt,
                                               const int2* __restrict__ bkt,
                                               const float* __restrict__ gemb0,
                                               const float* __restrict__ iemb0,
                                               const float* __restrict__ ui2item,
                                               float* __restrict__ gt1,
                                               float* __restrict__ gt3) {
    int row = blockIdx.x * 8 + (threadIdx.x >> 5);
    if (row >= 2 * G_N) return;
    int g = (row < G_N) ? row : row - G_N;
    const float* x1 = gemb0;
    const float* x2 = (row < G_N) ? iemb0 : ui2item;
    const int split = G_N;
    float* out = (row < G_N) ? gt1 : gt3;
    int d = threadIdx.x & 31;
    int deg = cnt[g];
    if (deg > CAP) deg = CAP;
    const int2* bk = bkt + (size_t)g * CAP;
    float acc = 0.f;
    int j = 0;
    for (; j + 3 < deg; j += 4) {
        int2 e0 = bk[j], e1 = bk[j + 1], e2 = bk[j + 2], e3 = bk[j + 3];
        float g0 = GATHER(e0), g1 = GATHER(e1), g2 = GATHER(e2), g3 = GATHER(e3);
        acc = fmaf(__int_as_float(e0.y), g0, acc);
        acc = fmaf(__int_as_float(e1.y), g1, acc);
        acc = fmaf(__int_as_float(e2.y), g2, acc);
        acc = fmaf(__int_as_float(e3.y), g3, acc);
    }
    for (; j < deg; ++j) {
        int2 e = bk[j];
        acc = fmaf(__int_as_float(e.y), GATHER(e), acc);
    }
    out[(size_t)g * 32 + d] = acc;
}
#undef GATHER

// ---------------- fused means ----------------

__global__ __launch_bounds__(256) void mean_ui(const float* __restrict__ uemb,
                                               const float* __restrict__ iemb0,
                                               const float* __restrict__ ui1,
                                               const float* __restrict__ ui2,
                                               const float* __restrict__ ui3,
                                               float* __restrict__ uefu,
                                               float* __restrict__ accu,
                                               float* __restrict__ iefu) {
    int idx = blockIdx.x * 256 + threadIdx.x;
    if (idx >= UI_N * 32) return;
    const int UOFF = U_N * 32;
    float base = (idx < UOFF) ? uemb[idx] : iemb0[idx - UOFF];
    float m = 0.25f * (base + ui1[idx] + ui2[idx] + ui3[idx]);
    if (idx < UOFF) { uefu[idx] = m; accu[idx] = m; }
    else iefu[idx - UOFF] = m;
}

__global__ __launch_bounds__(256) void mean_gi_items(const float* __restrict__ iefu,
                                                     const float* __restrict__ gi1,
                                                     const float* __restrict__ gi2,
                                                     const float* __restrict__ gi3,
                                                     float* __restrict__ iemb,
                                                     float* __restrict__ iacc) {
    int idx = blockIdx.x * 256 + threadIdx.x;
    if (idx >= I_N * 32) return;
    const int GOFF = G_N * 32;
    float m = 0.25f * (iefu[idx] + gi1[GOFF + idx] + gi2[GOFF + idx] + gi3[GOFF + idx]);
    iemb[idx] = m;
    iacc[idx] = m;
}

// ---------------- dense via MFMA, block-level K-split (atomic-free) ----------------

// Pack x[N,32] fp32 -> bf16 B-fragment layout for mfma_f32_16x16x32_bf16.
__global__ __launch_bounds__(256) void pack_xb(const float* __restrict__ x,
                                               short* __restrict__ XB, int N, int ktiles) {
    int idx = blockIdx.x * 256 + threadIdx.x;
    int total = ktiles * 2 * 64;
    if (idx >= total) return;
    int lane = idx & 63;
    int th = idx >> 6;
    int h = th & 1;
    int t = th >> 1;
    int q = lane >> 4;
    int n = (lane & 15) + h * 16;
    short v[8];
#pragma unroll
    for (int j = 0; j < 8; ++j) {
        int c = t * 32 + q * 8 + j;
        v[j] = (c < N) ? f32_to_bf16(x[(size_t)c * 32 + n]) : (short)0;
    }
    short* dst = XB + (size_t)idx * 8;
#pragma unroll
    for (int j = 0; j < 8; ++j) dst[j] = v[j];
}

// One block (512 thr = 8 waves) per 16-row strip. Wave w covers ktiles t=w,w+8,...
// LDS reduce -> plain stores (no atomics).
//   add1==null : out[o] = sum                      (pass 1)
//   add1!=null : out[o] = out[o] + add1[o] + sum   (pass 2)
__global__ __launch_bounds__(512) void dense_mfma_b(const float* __restrict__ A,
                                                    const short* __restrict__ XB,
                                                    float* __restrict__ out,
                                                    const float* __restrict__ add1,
                                                    int N, int ktiles) {
    __shared__ float red[8 * 512];   // 16 KB
    int tid = threadIdx.x;
    int w = tid >> 6;
    int lane = tid & 63;
    int r0 = blockIdx.x << 4;
    int m = lane & 15;
    int q = lane >> 4;
    const float* arow = A + (size_t)(r0 + m) * N + q * 8;
    const bf16x8* xb = (const bf16x8*)XB;
    f32x4 acc0 = {0.f, 0.f, 0.f, 0.f};
    f32x4 acc1 = {0.f, 0.f, 0.f, 0.f};
    for (int t = w; t < ktiles; t += 8) {
        int c0 = t * 32;
        bf16x8 afrag;
        if (c0 + 32 <= N) {
            float4 lo = *(const float4*)(arow + c0);
            float4 hi = *(const float4*)(arow + c0 + 4);
            afrag[0] = f32_to_bf16(lo.x); afrag[1] = f32_to_bf16(lo.y);
            afrag[2] = f32_to_bf16(lo.z); afrag[3] = f32_to_bf16(lo.w);
            afrag[4] = f32_to_bf16(hi.x); afrag[5] = f32_to_bf16(hi.y);
            afrag[6] = f32_to_bf16(hi.z); afrag[7] = f32_to_bf16(hi.w);
        } else {                                             // tail k-tile (U: c0=9984)
#pragma unroll
            for (int j = 0; j < 8; ++j) {
                int c = c0 + q * 8 + j;
                afrag[j] = (c < N) ? f32_to_bf16(arow[c0 + j]) : (short)0;
            }
        }
        bf16x8 b0 = xb[(size_t)(t * 2 + 0) * 64 + lane];
        bf16x8 b1 = xb[(size_t)(t * 2 + 1) * 64 + lane];
        acc0 = __builtin_amdgcn_mfma_f32_16x16x32_bf16(afrag, b0, acc0, 0, 0, 0);
        acc1 = __builtin_amdgcn_mfma_f32_16x16x32_bf16(afrag, b1, acc1, 0, 0, 0);
    }
    // partials to LDS: C/D layout col = lane&15 (m), row = (lane>>4)*4 + i
    float* my = red + w * 512;
#pragma unroll
    for (int i = 0; i < 4; ++i) {
        my[(q * 4 + i) * 32 + m]      = acc0[i];
        my[(q * 4 + i) * 32 + m + 16] = acc1[i];
    }
    __syncthreads();
    float s = red[tid];
#pragma unroll
    for (int wv = 1; wv < 8; ++wv) s += red[wv * 512 + tid];
    int row = tid >> 5;          // 0..15 within strip
    int col = tid & 31;
    size_t o = (size_t)(r0 + row) * 32 + col;
    out[o] = add1 ? (out[o] + add1[o] + s) : s;
}

// ---------------- fused mean_g + pool + gate + final mix ----------------
__global__ __launch_bounds__(256) void pool_gate_mix(const int* __restrict__ users,
                                                     const float* __restrict__ mask,
                                                     const float* __restrict__ accu,
                                                     const float* __restrict__ gemb0,
                                                     const float* __restrict__ gt1,
                                                     const float* __restrict__ gi2,
                                                     const float* __restrict__ gt3,
                                                     const float* __restrict__ W1,
                                                     const float* __restrict__ b1,
                                                     const float* __restrict__ w2,
                                                     const float* __restrict__ b2,
                                                     float* __restrict__ gfin) {
    int g = blockIdx.x * 8 + (threadIdx.x >> 5);
    if (g >= G_N) return;
    int j = threadIdx.x & 31;
    size_t gj = (size_t)g * 32 + j;
    float ge = 0.25f * (gemb0[gj] + gt1[gj] + gi2[gj] + gt3[gj]);   // mean_g inline
    // pool
    float gl = 0.f;
#pragma unroll
    for (int l = 0; l < L_MEM; ++l) {
        int u = users[g * L_MEM + l];
        gl = fmaf(mask[g * L_MEM + l], accu[(size_t)u * 32 + j], gl);
    }
    // gate(ge) and gate(gl)
    float h1 = b1[j], h2 = b1[j];
#pragma unroll
    for (int k = 0; k < 32; ++k) {
        float w = W1[k * 32 + j];
        h1 = fmaf(__shfl(ge, k, 32), w, h1);
        h2 = fmaf(__shfl(gl, k, 32), w, h2);
    }
    float w2j = w2[j];
    float t1 = fmaxf(h1, 0.f) * w2j;
    float t2 = fmaxf(h2, 0.f) * w2j;
#pragma unroll
    for (int off = 16; off >= 1; off >>= 1) {
        t1 += __shfl_xor(t1, off, 32);
        t2 += __shfl_xor(t2, off, 32);
    }
    float bb = b2[0];
    float wa = 1.f / (1.f + expf(-(t1 + bb)));
    float wb = 1.f / (1.f + expf(-(t2 + bb)));
    gfin[gj] = wa * ge + wb * gl;
}

__global__ __launch_bounds__(256) void predict_kernel(const int* __restrict__ gidx,
                                                      const int* __restrict__ iidx,
                                                      const float* __restrict__ gfin,
                                                      const float* __restrict__ iacc,
                                                      const float* __restrict__ pw1,
                                                      const float* __restrict__ pb1,
                                                      const float* __restrict__ pw2,
                                                      const float* __restrict__ pb2,
                                                      float* __restrict__ out) {
    int b = blockIdx.x * 256 + threadIdx.x;
    if (b >= B_N) return;
    const float* ge = gfin + (size_t)gidx[b] * 32;
    const float* ie = iacc + (size_t)iidx[b] * 32;
    float p[8];
#pragma unroll
    for (int j = 0; j < 8; ++j) p[j] = pb1[j];
    for (int d = 0; d < 32; ++d) {
        float t = ge[d] * ie[d];
#pragma unroll
        for (int j = 0; j < 8; ++j) p[j] = fmaf(t, pw1[d * 8 + j], p[j]);
    }
    float s = pb2[0];
#pragma unroll
    for (int j = 0; j < 8; ++j) s = fmaf(fmaxf(p[j], 0.f), pw2[j], s);
    out[b] = 1.f / (1.f + expf(-s));
}

// ---------------- launcher ----------------

extern "C" void kernel_launch(void* const* d_in, const int* in_sizes, int n_in,
                              void* d_out, int out_size, void* d_ws, size_t ws_size,
                              hipStream_t stream) {
    const int*   gin   = (const int*)d_in[0];
    const int*   iin   = (const int*)d_in[1];
    const float* uemb  = (const float*)d_in[2];
    const float* gemb0 = (const float*)d_in[3];
    const float* iemb0 = (const float*)d_in[4];
    const int*   uir   = (const int*)d_in[5];
    const int*   uic   = (const int*)d_in[6];
    const float* uiv   = (const float*)d_in[7];
    const int*   gir   = (const int*)d_in[8];
    const int*   gic   = (const int*)d_in[9];
    const float* giv   = (const float*)d_in[10];
    const float* ov_u  = (const float*)d_in[11];
    const float* ov_i  = (const float*)d_in[12];
    const int*   agu   = (const int*)d_in[13];
    const float* agm   = (const float*)d_in[14];
    const float* gw1   = (const float*)d_in[15];
    const float* gb1   = (const float*)d_in[16];
    const float* gw2   = (const float*)d_in[17];
    const float* gb2   = (const float*)d_in[18];
    const float* pw1   = (const float*)d_in[19];
    const float* pb1   = (const float*)d_in[20];
    const float* pw2   = (const float*)d_in[21];
    const float* pb2   = (const float*)d_in[22];
    float* out = (float*)d_out;

    const int KT_U = (U_N + 31) / 32;   // 313
    const int KT_I = I_N / 32;          // 250

    char* wp = (char*)d_ws;
    auto alloc = [&](size_t nbytes) -> void* {
        void* p = (void*)wp;
        wp += (nbytes + 255) & ~(size_t)255;
        return p;
    };
    // zero-init region: counters (adjacent -> one memset)
    int*   cnt_ui = (int*)alloc((size_t)UI_N * 4);
    int*   cnt_gi = (int*)alloc((size_t)GI_N * 4);
    size_t zbytes = (size_t)(wp - (char*)cnt_ui);

    int2*  bkt_ui = (int2*)alloc((size_t)UI_N * CAP * 8);
    int2*  bkt_gi = (int2*)alloc((size_t)GI_N * CAP * 8);
    float* uea  = (float*)alloc((size_t)U_N * 32 * 4);
    float* ita  = (float*)alloc((size_t)I_N * 32 * 4);
    float* ui1  = (float*)alloc((size_t)UI_N * 32 * 4);
    float* ui2  = (float*)alloc((size_t)UI_N * 32 * 4);
    float* ui3  = (float*)alloc((size_t)UI_N * 32 * 4);
    float* gi1  = (float*)alloc((size_t)GI_N * 32 * 4);
    float* gi2  = (float*)alloc((size_t)GI_N * 32 * 4);
    float* gi3  = (float*)alloc((size_t)GI_N * 32 * 4);
    float* uefu = (float*)alloc((size_t)U_N * 32 * 4);
    float* iefu = (float*)alloc((size_t)I_N * 32 * 4);
    float* iemb = (float*)alloc((size_t)I_N * 32 * 4);
    float* gt1  = (float*)alloc((size_t)G_N * 32 * 4);
    float* gt3  = (float*)alloc((size_t)G_N * 32 * 4);
    float* accu = (float*)alloc((size_t)U_N * 32 * 4);
    float* gfin = (float*)alloc((size_t)G_N * 32 * 4);
    float* iacc = (float*)alloc((size_t)I_N * 32 * 4);
    short* xbu  = (short*)alloc((size_t)KT_U * 2 * 64 * 8 * 2);
    short* xbi  = (short*)alloc((size_t)KT_I * 2 * 64 * 8 * 2);

    // --- buckets (one memset, one kernel) ---
    (void)hipMemsetAsync(cnt_ui, 0, zbytes, stream);
    bucket_fill2<<<cdiv(NNZ_UI + NNZ_GI, 256), 256, 0, stream>>>(
        uir, uic, uiv, gir, gic, giv, cnt_ui, cnt_gi, bkt_ui, bkt_gi);

    // --- user-item propagation (3 layers; layer1 reads split sources) ---
    spmm_split<<<cdiv(UI_N, 8), 256, 0, stream>>>(cnt_ui, bkt_ui, uemb, iemb0, U_N, ui1, UI_N);
    spmm_split<<<cdiv(UI_N, 8), 256, 0, stream>>>(cnt_ui, bkt_ui, ui1, ui1 + (size_t)U_N * 32, U_N, ui2, UI_N);
    spmm_split<<<cdiv(UI_N, 8), 256, 0, stream>>>(cnt_ui, bkt_ui, ui2, ui2 + (size_t)U_N * 32, U_N, ui3, UI_N);
    // g_layers odd terms (independent of ui3; needs ui2 item part)
    spmm_g2<<<cdiv(2 * G_N, 8), 256, 0, stream>>>(cnt_gi, bkt_gi, gemb0, iemb0,
                                                  ui2 + (size_t)U_N * 32, gt1, gt3);
    mean_ui<<<cdiv(UI_N * 32, 256), 256, 0, stream>>>(uemb, iemb0, ui1, ui2, ui3, uefu, accu, iefu);

    // --- group-item propagation ---
    spmm_split<<<cdiv(GI_N, 8), 256, 0, stream>>>(cnt_gi, bkt_gi, gemb0, iefu, G_N, gi1, GI_N);
    spmm_split<<<cdiv(GI_N, 8), 256, 0, stream>>>(cnt_gi, bkt_gi, gi1, gi1 + (size_t)G_N * 32, G_N, gi2, GI_N);
    spmm_split<<<cdiv(GI_N, 8), 256, 0, stream>>>(cnt_gi, bkt_gi, gi2, gi2 + (size_t)G_N * 32, G_N, gi3, GI_N);
    mean_gi_items<<<cdiv(I_N * 32, 256), 256, 0, stream>>>(iefu, gi1, gi2, gi3, iemb, iacc);

    // --- social user: accu = uefu + Ov@uefu + Ov@(Ov@uefu), atomic-free ---
    const int U_STRIPS = U_N / 16, I_STRIPS = I_N / 16;
    pack_xb<<<cdiv(KT_U * 128, 256), 256, 0, stream>>>(uefu, xbu, U_N, KT_U);
    dense_mfma_b<<<U_STRIPS, 512, 0, stream>>>(ov_u, xbu, uea, nullptr, U_N, KT_U);
    pack_xb<<<cdiv(KT_U * 128, 256), 256, 0, stream>>>(uea, xbu, U_N, KT_U);
    dense_mfma_b<<<U_STRIPS, 512, 0, stream>>>(ov_u, xbu, accu, uea, U_N, KT_U);

    // --- pool + gate + final mix (mean_g fused) ---
    pool_gate_mix<<<cdiv(G_N, 8), 256, 0, stream>>>(agu, agm, accu, gemb0, gt1, gi2, gt3,
                                                    gw1, gb1, gw2, gb2, gfin);

    // --- item overlap: iacc = iemb + Ov@iemb + Ov@(Ov@iemb), atomic-free ---
    pack_xb<<<cdiv(KT_I * 128, 256), 256, 0, stream>>>(iemb, xbi, I_N, KT_I);
    dense_mfma_b<<<I_STRIPS, 512, 0, stream>>>(ov_i, xbi, ita, nullptr, I_N, KT_I);
    pack_xb<<<cdiv(KT_I * 128, 256), 256, 0, stream>>>(ita, xbi, I_N, KT_I);
    dense_mfma_b<<<I_STRIPS, 512, 0, stream>>>(ov_i, xbi, iacc, ita, I_N, KT_I);

    // --- predict ---
    predict_kernel<<<cdiv(B_N, 256), 256, 0, stream>>>(gin, iin, gfin, iacc,
                                                       pw1, pb1, pw2, pb2, out);
}

// Round 9
// 1080.693 us; speedup vs baseline: 1.0237x; 1.0237x over previous
//
#include <hip/hip_runtime.h>
#include <math.h>

#define U_N 10000
#define G_N 3000
#define I_N 8000
#define D_N 32
#define NNZ_UI 720000
#define NNZ_GI 440000
#define L_MEM 20
#define B_N 4096
#define UI_N (U_N + I_N)   // 18000
#define GI_N (G_N + I_N)   // 11000
#define CAP 128            // max degree (Poisson(40); P(>128) ~ 1e-26)

static __host__ int cdiv(int a, int b) { return (a + b - 1) / b; }

typedef __attribute__((ext_vector_type(8))) short bf16x8;
typedef __attribute__((ext_vector_type(4))) float f32x4;

__device__ __forceinline__ short f32_to_bf16(float f) {
    unsigned u = __float_as_uint(f);
    unsigned r = (u + 0x7FFFu + ((u >> 16) & 1u)) >> 16;   // RTNE
    return (short)r;
}

// ---------------- sparse: bucket build (both graphs), one launch ----------------

__global__ __launch_bounds__(256) void bucket_fill2(const int* __restrict__ uir,
                                                    const int* __restrict__ uic,
                                                    const float* __restrict__ uiv,
                                                    const int* __restrict__ gir,
                                                    const int* __restrict__ gic,
                                                    const float* __restrict__ giv,
                                                    int* __restrict__ cnt_ui,
                                                    int* __restrict__ cnt_gi,
                                                    int2* __restrict__ bkt_ui,
                                                    int2* __restrict__ bkt_gi) {
    int i = blockIdx.x * 256 + threadIdx.x;
    if (i < NNZ_UI) {
        int r = uir[i];
        int pos = atomicAdd(&cnt_ui[r], 1);
        if (pos < CAP) {
            int2 e; e.x = uic[i]; e.y = __float_as_int(uiv[i]);
            bkt_ui[(size_t)r * CAP + pos] = e;
        }
        return;
    }
    int k = i - NNZ_UI;
    if (k < NNZ_GI) {
        int r = gir[k];
        int pos = atomicAdd(&cnt_gi[r], 1);
        if (pos < CAP) {
            int2 e; e.x = gic[k]; e.y = __float_as_int(giv[k]);
            bkt_gi[(size_t)r * CAP + pos] = e;
        }
    }
}

// dedupe the item indices referenced by predict -> compact rowlist
__global__ __launch_bounds__(256) void mark_items(const int* __restrict__ iidx,
                                                  int* __restrict__ iflags,
                                                  int* __restrict__ icount,
                                                  int* __restrict__ ilist) {
    int b = blockIdx.x * 256 + threadIdx.x;
    if (b >= B_N) return;
    int it = iidx[b];
    if (it < 0 || it >= I_N) return;                 // hard clamp (should not happen)
    if (atomicExch(&iflags[it], 1) == 0) {
        int p = atomicAdd(icount, 1);
        if (p < B_N) ilist[p] = it;
    }
}

// ---------------- split-source gather SPMM ----------------
#define GATHER(e) ((e.x < split) ? x1[(size_t)e.x * 32 + d] \
                                 : x2[(size_t)(e.x - split) * 32 + d])

// out[row,d] = sum_j val_j * X[col_j, d], X = concat(x1[0:split], x2[...]).
// rows processed: row0 .. nrows-1
__global__ __launch_bounds__(256) void spmm_split(const int* __restrict__ cnt,
                                                  const int2* __restrict__ bkt,
                                                  const float* __restrict__ x1,
                                                  const float* __restrict__ x2,
                                                  int split,
                                                  float* __restrict__ out,
                                                  int row0, int nrows) {
    int row = row0 + blockIdx.x * 8 + (threadIdx.x >> 5);
    if (row >= nrows) return;
    int d = threadIdx.x & 31;
    int deg = cnt[row];
    if (deg > CAP) deg = CAP;
    const int2* bk = bkt + (size_t)row * CAP;
    float acc = 0.f;
    int j = 0;
    for (; j + 3 < deg; j += 4) {
        int2 e0 = bk[j], e1 = bk[j + 1], e2 = bk[j + 2], e3 = bk[j + 3];
        float g0 = GATHER(e0), g1 = GATHER(e1), g2 = GATHER(e2), g3 = GATHER(e3);
        acc = fmaf(__int_as_float(e0.y), g0, acc);
        acc = fmaf(__int_as_float(e1.y), g1, acc);
        acc = fmaf(__int_as_float(e2.y), g2, acc);
        acc = fmaf(__int_as_float(e3.y), g3, acc);
    }
    for (; j < deg; ++j) {
        int2 e = bk[j];
        acc = fmaf(__int_as_float(e.y), GATHER(e), acc);
    }
    out[(size_t)row * 32 + d] = acc;
}

// gt1 (rows 0..G-1, x2=iemb0) and gt3 (rows G..2G-1 of virtual space, x2=ui2 item part)
// merged into one launch; both use bkt_gi rows < G, x1=gemb0, split=G_N.
__global__ __launch_bounds__(256) void spmm_g2(const int* __restrict__ cnt,
                                               const int2* __restrict__ bkt,
                                               const float* __restrict__ gemb0,
                                               const float* __restrict__ iemb0,
                                               const float* __restrict__ ui2item,
                                               float* __restrict__ gt1,
                                               float* __restrict__ gt3) {
    int row = blockIdx.x * 8 + (threadIdx.x >> 5);
    if (row >= 2 * G_N) return;
    int g = (row < G_N) ? row : row - G_N;
    const float* x1 = gemb0;
    const float* x2 = (row < G_N) ? iemb0 : ui2item;
    const int split = G_N;
    float* out = (row < G_N) ? gt1 : gt3;
    int d = threadIdx.x & 31;
    int deg = cnt[g];
    if (deg > CAP) deg = CAP;
    const int2* bk = bkt + (size_t)g * CAP;
    float acc = 0.f;
    int j = 0;
    for (; j + 3 < deg; j += 4) {
        int2 e0 = bk[j], e1 = bk[j + 1], e2 = bk[j + 2], e3 = bk[j + 3];
        float g0 = GATHER(e0), g1 = GATHER(e1), g2 = GATHER(e2), g3 = GATHER(e3);
        acc = fmaf(__int_as_float(e0.y), g0, acc);
        acc = fmaf(__int_as_float(e1.y), g1, acc);
        acc = fmaf(__int_as_float(e2.y), g2, acc);
        acc = fmaf(__int_as_float(e3.y), g3, acc);
    }
    for (; j < deg; ++j) {
        int2 e = bk[j];
        acc = fmaf(__int_as_float(e.y), GATHER(e), acc);
    }
    out[(size_t)g * 32 + d] = acc;
}
#undef GATHER

// ---------------- fused means ----------------

__global__ __launch_bounds__(256) void mean_ui(const float* __restrict__ uemb,
                                               const float* __restrict__ iemb0,
                                               const float* __restrict__ ui1,
                                               const float* __restrict__ ui2,
                                               const float* __restrict__ ui3,
                                               float* __restrict__ uefu,
                                               float* __restrict__ accu,
                                               float* __restrict__ iefu) {
    int idx = blockIdx.x * 256 + threadIdx.x;
    if (idx >= UI_N * 32) return;
    const int UOFF = U_N * 32;
    float base = (idx < UOFF) ? uemb[idx] : iemb0[idx - UOFF];
    float m = 0.25f * (base + ui1[idx] + ui2[idx] + ui3[idx]);
    if (idx < UOFF) { uefu[idx] = m; accu[idx] = m; }
    else iefu[idx - UOFF] = m;
}

__global__ __launch_bounds__(256) void mean_gi_items(const float* __restrict__ iefu,
                                                     const float* __restrict__ gi1,
                                                     const float* __restrict__ gi2,
                                                     const float* __restrict__ gi3,
                                                     float* __restrict__ iemb,
                                                     float* __restrict__ iacc) {
    int idx = blockIdx.x * 256 + threadIdx.x;
    if (idx >= I_N * 32) return;
    const int GOFF = G_N * 32;
    float m = 0.25f * (iefu[idx] + gi1[GOFF + idx] + gi2[GOFF + idx] + gi3[GOFF + idx]);
    iemb[idx] = m;
    iacc[idx] = m;
}

// ---------------- dense via MFMA, block-level K-split (atomic-free) ----------------

// Pack x[N,32] fp32 -> bf16 B-fragment layout for mfma_f32_16x16x32_bf16.
__global__ __launch_bounds__(256) void pack_xb(const float* __restrict__ x,
                                               short* __restrict__ XB, int N, int ktiles) {
    int idx = blockIdx.x * 256 + threadIdx.x;
    int total = ktiles * 2 * 64;
    if (idx >= total) return;
    int lane = idx & 63;
    int th = idx >> 6;
    int h = th & 1;
    int t = th >> 1;
    int q = lane >> 4;
    int n = (lane & 15) + h * 16;
    short v[8];
#pragma unroll
    for (int j = 0; j < 8; ++j) {
        int c = t * 32 + q * 8 + j;
        v[j] = (c < N) ? f32_to_bf16(x[(size_t)c * 32 + n]) : (short)0;
    }
    short* dst = XB + (size_t)idx * 8;
#pragma unroll
    for (int j = 0; j < 8; ++j) dst[j] = v[j];
}

// One block (512 thr = 8 waves) per 16-row strip. Wave w covers ktiles t=w,w+8,...
// LDS reduce -> plain stores (no atomics).
//   add1==null : out[o] = sum                      (pass 1)
//   add1!=null : out[o] = out[o] + add1[o] + sum   (pass 2)
__global__ __launch_bounds__(512) void dense_mfma_b(const float* __restrict__ A,
                                                    const short* __restrict__ XB,
                                                    float* __restrict__ out,
                                                    const float* __restrict__ add1,
                                                    int N, int ktiles) {
    __shared__ float red[8 * 512];   // 16 KB
    int tid = threadIdx.x;
    int w = tid >> 6;
    int lane = tid & 63;
    int r0 = blockIdx.x << 4;
    int m = lane & 15;
    int q = lane >> 4;
    const float* arow = A + (size_t)(r0 + m) * N + q * 8;
    const bf16x8* xb = (const bf16x8*)XB;
    f32x4 acc0 = {0.f, 0.f, 0.f, 0.f};
    f32x4 acc1 = {0.f, 0.f, 0.f, 0.f};
    for (int t = w; t < ktiles; t += 8) {
        int c0 = t * 32;
        bf16x8 afrag;
        if (c0 + 32 <= N) {
            float4 lo = *(const float4*)(arow + c0);
            float4 hi = *(const float4*)(arow + c0 + 4);
            afrag[0] = f32_to_bf16(lo.x); afrag[1] = f32_to_bf16(lo.y);
            afrag[2] = f32_to_bf16(lo.z); afrag[3] = f32_to_bf16(lo.w);
            afrag[4] = f32_to_bf16(hi.x); afrag[5] = f32_to_bf16(hi.y);
            afrag[6] = f32_to_bf16(hi.z); afrag[7] = f32_to_bf16(hi.w);
        } else {                                             // tail k-tile (U: c0=9984)
#pragma unroll
            for (int j = 0; j < 8; ++j) {
                int c = c0 + q * 8 + j;
                afrag[j] = (c < N) ? f32_to_bf16(arow[c0 + j]) : (short)0;
            }
        }
        bf16x8 b0 = xb[(size_t)(t * 2 + 0) * 64 + lane];
        bf16x8 b1 = xb[(size_t)(t * 2 + 1) * 64 + lane];
        acc0 = __builtin_amdgcn_mfma_f32_16x16x32_bf16(afrag, b0, acc0, 0, 0, 0);
        acc1 = __builtin_amdgcn_mfma_f32_16x16x32_bf16(afrag, b1, acc1, 0, 0, 0);
    }
    // partials to LDS: C/D layout col = lane&15 (m), row = (lane>>4)*4 + i
    float* my = red + w * 512;
#pragma unroll
    for (int i = 0; i < 4; ++i) {
        my[(q * 4 + i) * 32 + m]      = acc0[i];
        my[(q * 4 + i) * 32 + m + 16] = acc1[i];
    }
    __syncthreads();
    float s = red[tid];
#pragma unroll
    for (int wv = 1; wv < 8; ++wv) s += red[wv * 512 + tid];
    int row = tid >> 5;          // 0..15 within strip
    int col = tid & 31;
    size_t o = (size_t)(r0 + row) * 32 + col;
    out[o] = add1 ? (out[o] + add1[o] + s) : s;
}

// Trimmed pass-2: rows from rowlist[0:*rowcount]; out[r] = out[r] + add1[r] + (A@XB)[r].
// Each listed row is owned by exactly one block -> race-free plain RMW.
__global__ __launch_bounds__(512) void dense_mfma_trim(const float* __restrict__ A,
                                                       const short* __restrict__ XB,
                                                       float* __restrict__ out,
                                                       const float* __restrict__ add1,
                                                       const int* __restrict__ rowlist,
                                                       const int* __restrict__ rowcount,
                                                       int N, int ktiles) {
    __shared__ float red[8 * 512];   // 16 KB
    int cnt = *rowcount;
    if (cnt < 1) return;
    if (cnt > B_N) cnt = B_N;
    int r0 = blockIdx.x << 4;
    if (r0 >= cnt) return;           // uniform across block
    int tid = threadIdx.x;
    int w = tid >> 6;
    int lane = tid & 63;
    int m = lane & 15;
    int q = lane >> 4;
    int ci = r0 + m;
    if (ci >= cnt) ci = cnt - 1;     // cnt>=1 so ci>=0
    int arow_g = rowlist[ci];
    if (arow_g < 0 || arow_g >= I_N) arow_g = 0;   // hard clamp
    const float* arow = A + (size_t)arow_g * N + q * 8;
    const bf16x8* xb = (const bf16x8*)XB;
    f32x4 acc0 = {0.f, 0.f, 0.f, 0.f};
    f32x4 acc1 = {0.f, 0.f, 0.f, 0.f};
    for (int t = w; t < ktiles; t += 8) {
        int c0 = t * 32;             // N=8000 divisible by 32: no tail
        float4 lo = *(const float4*)(arow + c0);
        float4 hi = *(const float4*)(arow + c0 + 4);
        bf16x8 afrag;
        afrag[0] = f32_to_bf16(lo.x); afrag[1] = f32_to_bf16(lo.y);
        afrag[2] = f32_to_bf16(lo.z); afrag[3] = f32_to_bf16(lo.w);
        afrag[4] = f32_to_bf16(hi.x); afrag[5] = f32_to_bf16(hi.y);
        afrag[6] = f32_to_bf16(hi.z); afrag[7] = f32_to_bf16(hi.w);
        bf16x8 b0 = xb[(size_t)(t * 2 + 0) * 64 + lane];
        bf16x8 b1 = xb[(size_t)(t * 2 + 1) * 64 + lane];
        acc0 = __builtin_amdgcn_mfma_f32_16x16x32_bf16(afrag, b0, acc0, 0, 0, 0);
        acc1 = __builtin_amdgcn_mfma_f32_16x16x32_bf16(afrag, b1, acc1, 0, 0, 0);
    }
    float* my = red + w * 512;
#pragma unroll
    for (int i = 0; i < 4; ++i) {
        my[(q * 4 + i) * 32 + m]      = acc0[i];
        my[(q * 4 + i) * 32 + m + 16] = acc1[i];
    }
    __syncthreads();
    float s = red[tid];
#pragma unroll
    for (int wv = 1; wv < 8; ++wv) s += red[wv * 512 + tid];
    int row = tid >> 5;          // 0..15 within strip
    int col = tid & 31;
    int gidx = r0 + row;
    if (gidx < cnt) {
        int orow = rowlist[gidx];
        if (orow >= 0 && orow < I_N) {
            size_t o = (size_t)orow * 32 + col;
            out[o] = out[o] + add1[o] + s;
        }
    }
}

// ---------------- fused mean_g + pool + gate + final mix ----------------
__global__ __launch_bounds__(256) void pool_gate_mix(const int* __restrict__ users,
                                                     const float* __restrict__ mask,
                                                     const float* __restrict__ accu,
                                                     const float* __restrict__ gemb0,
                                                     const float* __restrict__ gt1,
                                                     const float* __restrict__ gi2,
                                                     const float* __restrict__ gt3,
                                                     const float* __restrict__ W1,
                                                     const float* __restrict__ b1,
                                                     const float* __restrict__ w2,
                                                     const float* __restrict__ b2,
                                                     float* __restrict__ gfin) {
    int g = blockIdx.x * 8 + (threadIdx.x >> 5);
    if (g >= G_N) return;
    int j = threadIdx.x & 31;
    size_t gj = (size_t)g * 32 + j;
    float ge = 0.25f * (gemb0[gj] + gt1[gj] + gi2[gj] + gt3[gj]);   // mean_g inline
    // pool
    float gl = 0.f;
#pragma unroll
    for (int l = 0; l < L_MEM; ++l) {
        int u = users[g * L_MEM + l];
        gl = fmaf(mask[g * L_MEM + l], accu[(size_t)u * 32 + j], gl);
    }
    // gate(ge) and gate(gl)
    float h1 = b1[j], h2 = b1[j];
#pragma unroll
    for (int k = 0; k < 32; ++k) {
        float w = W1[k * 32 + j];
        h1 = fmaf(__shfl(ge, k, 32), w, h1);
        h2 = fmaf(__shfl(gl, k, 32), w, h2);
    }
    float w2j = w2[j];
    float t1 = fmaxf(h1, 0.f) * w2j;
    float t2 = fmaxf(h2, 0.f) * w2j;
#pragma unroll
    for (int off = 16; off >= 1; off >>= 1) {
        t1 += __shfl_xor(t1, off, 32);
        t2 += __shfl_xor(t2, off, 32);
    }
    float bb = b2[0];
    float wa = 1.f / (1.f + expf(-(t1 + bb)));
    float wb = 1.f / (1.f + expf(-(t2 + bb)));
    gfin[gj] = wa * ge + wb * gl;
}

__global__ __launch_bounds__(256) void predict_kernel(const int* __restrict__ gidx,
                                                      const int* __restrict__ iidx,
                                                      const float* __restrict__ gfin,
                                                      const float* __restrict__ iacc,
                                                      const float* __restrict__ pw1,
                                                      const float* __restrict__ pb1,
                                                      const float* __restrict__ pw2,
                                                      const float* __restrict__ pb2,
                                                      float* __restrict__ out) {
    int b = blockIdx.x * 256 + threadIdx.x;
    if (b >= B_N) return;
    const float* ge = gfin + (size_t)gidx[b] * 32;
    const float* ie = iacc + (size_t)iidx[b] * 32;
    float p[8];
#pragma unroll
    for (int j = 0; j < 8; ++j) p[j] = pb1[j];
    for (int d = 0; d < 32; ++d) {
        float t = ge[d] * ie[d];
#pragma unroll
        for (int j = 0; j < 8; ++j) p[j] = fmaf(t, pw1[d * 8 + j], p[j]);
    }
    float s = pb2[0];
#pragma unroll
    for (int j = 0; j < 8; ++j) s = fmaf(fmaxf(p[j], 0.f), pw2[j], s);
    out[b] = 1.f / (1.f + expf(-s));
}

// ---------------- launcher ----------------

extern "C" void kernel_launch(void* const* d_in, const int* in_sizes, int n_in,
                              void* d_out, int out_size, void* d_ws, size_t ws_size,
                              hipStream_t stream) {
    const int*   gin   = (const int*)d_in[0];
    const int*   iin   = (const int*)d_in[1];
    const float* uemb  = (const float*)d_in[2];
    const float* gemb0 = (const float*)d_in[3];
    const float* iemb0 = (const float*)d_in[4];
    const int*   uir   = (const int*)d_in[5];
    const int*   uic   = (const int*)d_in[6];
    const float* uiv   = (const float*)d_in[7];
    const int*   gir   = (const int*)d_in[8];
    const int*   gic   = (const int*)d_in[9];
    const float* giv   = (const float*)d_in[10];
    const float* ov_u  = (const float*)d_in[11];
    const float* ov_i  = (const float*)d_in[12];
    const int*   agu   = (const int*)d_in[13];
    const float* agm   = (const float*)d_in[14];
    const float* gw1   = (const float*)d_in[15];
    const float* gb1   = (const float*)d_in[16];
    const float* gw2   = (const float*)d_in[17];
    const float* gb2   = (const float*)d_in[18];
    const float* pw1   = (const float*)d_in[19];
    const float* pb1   = (const float*)d_in[20];
    const float* pw2   = (const float*)d_in[21];
    const float* pb2   = (const float*)d_in[22];
    float* out = (float*)d_out;

    const int KT_U = (U_N + 31) / 32;   // 313
    const int KT_I = I_N / 32;          // 250

    char* wp = (char*)d_ws;
    auto alloc = [&](size_t nbytes) -> void* {
        void* p = (void*)wp;
        wp += (nbytes + 255) & ~(size_t)255;
        return p;
    };
    // zero-init region: counters + item flags + item count (adjacent -> one memset)
    int*   cnt_ui = (int*)alloc((size_t)UI_N * 4);
    int*   cnt_gi = (int*)alloc((size_t)GI_N * 4);
    int*   iflags = (int*)alloc((size_t)I_N * 4);
    int*   icount = (int*)alloc(4);
    size_t zbytes = (size_t)(wp - (char*)cnt_ui);
    int*   ilist  = (int*)alloc((size_t)B_N * 4);

    int2*  bkt_ui = (int2*)alloc((size_t)UI_N * CAP * 8);
    int2*  bkt_gi = (int2*)alloc((size_t)GI_N * CAP * 8);
    float* uea  = (float*)alloc((size_t)U_N * 32 * 4);
    float* ita  = (float*)alloc((size_t)I_N * 32 * 4);
    float* ui1  = (float*)alloc((size_t)UI_N * 32 * 4);
    float* ui2  = (float*)alloc((size_t)UI_N * 32 * 4);
    float* ui3  = (float*)alloc((size_t)UI_N * 32 * 4);
    float* gi1  = (float*)alloc((size_t)GI_N * 32 * 4);
    float* gi2  = (float*)alloc((size_t)GI_N * 32 * 4);
    float* gi3  = (float*)alloc((size_t)GI_N * 32 * 4);
    float* uefu = (float*)alloc((size_t)U_N * 32 * 4);
    float* iefu = (float*)alloc((size_t)I_N * 32 * 4);
    float* iemb = (float*)alloc((size_t)I_N * 32 * 4);
    float* gt1  = (float*)alloc((size_t)G_N * 32 * 4);
    float* gt3  = (float*)alloc((size_t)G_N * 32 * 4);
    float* accu = (float*)alloc((size_t)U_N * 32 * 4);
    float* gfin = (float*)alloc((size_t)G_N * 32 * 4);
    float* iacc = (float*)alloc((size_t)I_N * 32 * 4);
    short* xbu  = (short*)alloc((size_t)KT_U * 2 * 64 * 8 * 2);
    short* xbi  = (short*)alloc((size_t)KT_I * 2 * 64 * 8 * 2);

    // --- buckets + item dedupe (one memset, two kernels) ---
    (void)hipMemsetAsync(cnt_ui, 0, zbytes, stream);
    bucket_fill2<<<cdiv(NNZ_UI + NNZ_GI, 256), 256, 0, stream>>>(
        uir, uic, uiv, gir, gic, giv, cnt_ui, cnt_gi, bkt_ui, bkt_gi);
    mark_items<<<cdiv(B_N, 256), 256, 0, stream>>>(iin, iflags, icount, ilist);

    // --- user-item propagation (3 layers; layer1 reads split sources) ---
    spmm_split<<<cdiv(UI_N, 8), 256, 0, stream>>>(cnt_ui, bkt_ui, uemb, iemb0, U_N, ui1, 0, UI_N);
    spmm_split<<<cdiv(UI_N, 8), 256, 0, stream>>>(cnt_ui, bkt_ui, ui1, ui1 + (size_t)U_N * 32, U_N, ui2, 0, UI_N);
    spmm_split<<<cdiv(UI_N, 8), 256, 0, stream>>>(cnt_ui, bkt_ui, ui2, ui2 + (size_t)U_N * 32, U_N, ui3, 0, UI_N);
    // g_layers odd terms (independent of ui3; needs ui2 item part)
    spmm_g2<<<cdiv(2 * G_N, 8), 256, 0, stream>>>(cnt_gi, bkt_gi, gemb0, iemb0,
                                                  ui2 + (size_t)U_N * 32, gt1, gt3);
    mean_ui<<<cdiv(UI_N * 32, 256), 256, 0, stream>>>(uemb, iemb0, ui1, ui2, ui3, uefu, accu, iefu);

    // --- group-item propagation (gi3 only needed for item rows) ---
    spmm_split<<<cdiv(GI_N, 8), 256, 0, stream>>>(cnt_gi, bkt_gi, gemb0, iefu, G_N, gi1, 0, GI_N);
    spmm_split<<<cdiv(GI_N, 8), 256, 0, stream>>>(cnt_gi, bkt_gi, gi1, gi1 + (size_t)G_N * 32, G_N, gi2, 0, GI_N);
    spmm_split<<<cdiv(I_N, 8), 256, 0, stream>>>(cnt_gi, bkt_gi, gi2, gi2 + (size_t)G_N * 32, G_N, gi3, G_N, GI_N);
    mean_gi_items<<<cdiv(I_N * 32, 256), 256, 0, stream>>>(iefu, gi1, gi2, gi3, iemb, iacc);

    // --- social user: accu = uefu + Ov@uefu + Ov@(Ov@uefu), atomic-free ---
    const int U_STRIPS = U_N / 16, I_STRIPS = I_N / 16;
    pack_xb<<<cdiv(KT_U * 128, 256), 256, 0, stream>>>(uefu, xbu, U_N, KT_U);
    dense_mfma_b<<<U_STRIPS, 512, 0, stream>>>(ov_u, xbu, uea, nullptr, U_N, KT_U);
    pack_xb<<<cdiv(KT_U * 128, 256), 256, 0, stream>>>(uea, xbu, U_N, KT_U);
    dense_mfma_b<<<U_STRIPS, 512, 0, stream>>>(ov_u, xbu, accu, uea, U_N, KT_U);

    // --- pool + gate + final mix (mean_g fused) ---
    pool_gate_mix<<<cdiv(G_N, 8), 256, 0, stream>>>(agu, agm, accu, gemb0, gt1, gi2, gt3,
                                                    gw1, gb1, gw2, gb2, gfin);

    // --- item overlap: iacc = iemb + Ov@iemb + Ov@(Ov@iemb); pass2 trimmed to predicted rows ---
    pack_xb<<<cdiv(KT_I * 128, 256), 256, 0, stream>>>(iemb, xbi, I_N, KT_I);
    dense_mfma_b<<<I_STRIPS, 512, 0, stream>>>(ov_i, xbi, ita, nullptr, I_N, KT_I);
    pack_xb<<<cdiv(KT_I * 128, 256), 256, 0, stream>>>(ita, xbi, I_N, KT_I);
    dense_mfma_trim<<<cdiv(B_N, 16), 512, 0, stream>>>(ov_i, xbi, iacc, ita, ilist, icount, I_N, KT_I);

    // --- predict ---
    predict_kernel<<<cdiv(B_N, 256), 256, 0, stream>>>(gin, iin, gfin, iacc,
                                                       pw1, pb1, pw2, pb2, out);
}